// Round 11
// baseline (18622.838 us; speedup 1.0000x reference)
//
#include <hip/hip_runtime.h>

#define NRES 2048
#define NBLK 64    // sync participants: 4x fewer than R4
#define NTHR 1024  // 16 waves/block; per-wave work identical to R4
#define RBUF 4     // rotation depth; max inter-block skew 1 step -> >=3 race-free

typedef unsigned long long u64;
typedef unsigned int u32;

// ---------------- W transpose: Wt[j][i] = W[i][j] ----------------
__global__ __launch_bounds__(256) void transpose_k(const float* __restrict__ W,
                                                   float* __restrict__ Wt) {
  __shared__ float tile[32][33];
  const int tx = threadIdx.x, ty = threadIdx.y;
  const int x = blockIdx.x * 32 + tx;
  const int y0 = blockIdx.y * 32;
#pragma unroll
  for (int j = ty; j < 32; j += 8)
    tile[j][tx] = W[(size_t)(y0 + j) * NRES + x];
  __syncthreads();
  const int x2 = blockIdx.y * 32 + tx;
  const int y2 = blockIdx.x * 32;
#pragma unroll
  for (int j = ty; j < 32; j += 8)
    Wt[(size_t)(y2 + j) * NRES + x2] = tile[tx][j];
}

// ---------------- uproj GEMM: U[M,N] = X[M,K] @ B[K,N], fp32 ----------------
__global__ __launch_bounds__(256) void gemm_uproj(const float* __restrict__ X,
                                                  const float* __restrict__ B,
                                                  float* __restrict__ U,
                                                  int M, int N, int K) {
  __shared__ float As[16][128];  // As[k][m]
  __shared__ float Bs[16][128];  // Bs[k][n]
  const int tid = threadIdx.x;
  const int tx = tid & 15, ty = tid >> 4;
  const int m0 = blockIdx.y * 128, n0 = blockIdx.x * 128;

  float acc[8][8];
#pragma unroll
  for (int i = 0; i < 8; i++)
#pragma unroll
    for (int j = 0; j < 8; j++) acc[i][j] = 0.f;

  const int sam = tid >> 1, sak = (tid & 1) * 8;   // A staging: row, k-half
  const int sbk = tid >> 4, sbn = (tid & 15) * 8;  // B staging: k, n-start

  for (int k0 = 0; k0 < K; k0 += 16) {
    const float* ap = X + (size_t)(m0 + sam) * K + k0 + sak;
    float4 a0 = *(const float4*)(ap);
    float4 a1 = *(const float4*)(ap + 4);
    As[sak + 0][sam] = a0.x; As[sak + 1][sam] = a0.y;
    As[sak + 2][sam] = a0.z; As[sak + 3][sam] = a0.w;
    As[sak + 4][sam] = a1.x; As[sak + 5][sam] = a1.y;
    As[sak + 6][sam] = a1.z; As[sak + 7][sam] = a1.w;
    const float* bp = B + (size_t)(k0 + sbk) * N + n0 + sbn;
    *(float4*)&Bs[sbk][sbn]     = *(const float4*)(bp);
    *(float4*)&Bs[sbk][sbn + 4] = *(const float4*)(bp + 4);
    __syncthreads();
#pragma unroll
    for (int kk = 0; kk < 16; kk++) {
      float a[8], b[8];
      *(float4*)&a[0] = *(const float4*)&As[kk][ty * 8];
      *(float4*)&a[4] = *(const float4*)&As[kk][ty * 8 + 4];
      *(float4*)&b[0] = *(const float4*)&Bs[kk][tx * 8];
      *(float4*)&b[4] = *(const float4*)&Bs[kk][tx * 8 + 4];
#pragma unroll
      for (int i = 0; i < 8; i++)
#pragma unroll
        for (int j = 0; j < 8; j++) acc[i][j] += a[i] * b[j];
    }
    __syncthreads();
  }
#pragma unroll
  for (int i = 0; i < 8; i++) {
    float* dst = U + (size_t)(m0 + ty * 8 + i) * N + n0 + tx * 8;
    *(float4*)dst       = *(float4*)&acc[i][0];
    *(float4*)(dst + 4) = *(float4*)&acc[i][4];
  }
}

// ---------------- persistent ESN scan, tagged-value sync, 64 blocks --------
// 64 blocks x 1024 threads (16 waves), cooperative, 1 block/CU. Block b owns
// columns [32b, 32b+32): wave wv (0..15) half h -> j = 32b + 2wv + h;
// sub-lane s (0..31) holds W[:,j] elems {2s+64k, 2s+64k+1}, k=0..31
// (64 floats in VGPRs) -- per-wave layout IDENTICAL to the proven R4 kernel.
//
// Rationale (R10 post-mortem): guarded+paced polling changed nothing ->
// the publish->observe lag is not round-rate- or chain-limited; the one
// untested axis is PARTICIPANT COUNT. Every step 256 consumers pulled all
// 2048 words through the coherence point (~0.5M 8B sc1 requests/step plus
// ~35x re-poll). 64 consumers cut that 4x, and the per-step max-skew is
// over 64 blocks instead of 256.
//
// Sync: v_t[j] published as {tag=t+1, f32} via fire-and-forget agent atomic
// swap (commits at the coherence point). Poll branch-free: 2 words/thread,
// both in flight per round. v_lds double-buffered -> ONE barrier per step.
// v_old[j] in a register on the publishing lane. tanh = 1 - 2/(e^2x+1).
__global__ __launch_bounds__(1024, 1) void esn_scan(const float* __restrict__ Wt,
                                                    const float* __restrict__ W,
                                                    u64* vtag,
                                                    float* __restrict__ UY,
                                                    int T) {
  __shared__ float v_lds[2][NRES];
  const int b = blockIdx.x;
  const int tid = threadIdx.x;
  const int wv = tid >> 6;
  const int lane = tid & 63;
  const int h = lane >> 5;
  const int s = lane & 31;
  const int j = b * 32 + wv * 2 + h;

  // one-time: load column j of W into registers (coalesced via Wt)
  float2 w2[32];
  if (Wt) {
    const float2* wrow = (const float2*)(Wt + (size_t)j * NRES);
#pragma unroll
    for (int k = 0; k < 32; ++k) w2[k] = wrow[s + 32 * k];
  } else {
#pragma unroll
    for (int k = 0; k < 32; ++k) {
      w2[k].x = W[(size_t)(2 * s + 64 * k) * NRES + j];
      w2[k].y = W[(size_t)(2 * s + 64 * k + 1) * NRES + j];
    }
  }

  float vold = 0.f;  // v_{t-1}[j], live on s==0 lanes only
  v_lds[0][tid] = 0.f;
  v_lds[0][tid + NTHR] = 0.f;
  __syncthreads();

  for (int t = 0; t < T; ++t) {
    const int buf = t & 1;
    const size_t idx = (size_t)t * NRES + j;
    float u = (s == 0) ? UY[idx] : 0.f;  // in flight during the poll

    if (t > 0) {
      u64* src = vtag + (size_t)((t - 1) & (RBUF - 1)) * NRES;
      unsigned done = 0;
      while (done != 3u) {
        // branch-free: both words in flight every round (R3/R4 fastest form)
        u64 w0 = __hip_atomic_load(&src[tid], __ATOMIC_RELAXED,
                                   __HIP_MEMORY_SCOPE_AGENT);
        u64 w1 = __hip_atomic_load(&src[tid + NTHR], __ATOMIC_RELAXED,
                                   __HIP_MEMORY_SCOPE_AGENT);
        if (!(done & 1u) && (u32)(w0 >> 32) == (u32)t) {
          v_lds[buf][tid] = __uint_as_float((u32)w0);
          done |= 1u;
        }
        if (!(done & 2u) && (u32)(w1 >> 32) == (u32)t) {
          v_lds[buf][tid + NTHR] = __uint_as_float((u32)w1);
          done |= 2u;
        }
      }
      __syncthreads();
    }

    // dot(v, W[:,j]) : 32 x float2, 2-way LDS aliasing (free), 2 acc chains
    float acc0 = 0.f, acc1 = 0.f;
#pragma unroll
    for (int k = 0; k < 32; k += 2) {
      float2 va = *(const float2*)&v_lds[buf][2 * s + 64 * k];
      float2 vb = *(const float2*)&v_lds[buf][2 * s + 64 * (k + 1)];
      acc0 += w2[k].x * va.x + w2[k].y * va.y;
      acc1 += w2[k + 1].x * vb.x + w2[k + 1].y * vb.y;
    }
    float acc = acc0 + acc1;
    // butterfly reduce across the 32 sub-lanes of each half-wave
#pragma unroll
    for (int off = 16; off >= 1; off >>= 1) acc += __shfl_xor(acc, off);

    if (s == 0) {
      float xx = acc + u;
      float e = __expf(2.f * xx);        // v_exp_f32 path
      float th = 1.f - 2.f / (e + 1.f);  // == tanh(xx) exactly
      float vnew = 0.5f * vold + 0.5f * th;
      vold = vnew;
      UY[idx] = vnew;  // states[t][j]
      u64 w = ((u64)(u32)(t + 1) << 32) | (u64)__float_as_uint(vnew);
      (void)__hip_atomic_exchange(&vtag[(size_t)(t & (RBUF - 1)) * NRES + j],
                                  w, __ATOMIC_RELAXED,
                                  __HIP_MEMORY_SCOPE_AGENT);
    }
  }
}

extern "C" void kernel_launch(void* const* d_in, const int* in_sizes, int n_in,
                              void* d_out, int out_size, void* d_ws, size_t ws_size,
                              hipStream_t stream) {
  const float* x   = (const float*)d_in[0];
  const float* Win = (const float*)d_in[1];
  const float* W   = (const float*)d_in[2];
  float* U = (float*)d_out;

  const int T = out_size / NRES;  // 4096
  const int K = in_sizes[0] / T;  // 4096 (nInput)

  char* ws = (char*)d_ws;
  u64* vtag = (u64*)ws;  // [RBUF][NRES] = 64 KB @ 0
  const size_t vtag_bytes = (size_t)RBUF * NRES * sizeof(u64);
  float* Wt = nullptr;
  if (ws_size >= (1u << 20) + (size_t)NRES * NRES * sizeof(float))
    Wt = (float*)(ws + (1u << 20));  // 16 MB @ 1 MB

  // tags must be zeroed every launch (replays would otherwise see stale epochs)
  hipMemsetAsync(vtag, 0, vtag_bytes, stream);

  if (Wt) transpose_k<<<dim3(NRES / 32, NRES / 32), dim3(32, 8), 0, stream>>>(W, Wt);

  gemm_uproj<<<dim3(NRES / 128, T / 128), 256, 0, stream>>>(x, Win, U, T, NRES, K);

  void* args[] = {(void*)&Wt, (void*)&W, (void*)&vtag, (void*)&U, (void*)&T};
  hipLaunchCooperativeKernel((const void*)esn_scan, dim3(NBLK), dim3(NTHR), args,
                             0, stream);
}